// Round 7
// baseline (338.279 us; speedup 1.0000x reference)
//
#include <hip/hip_runtime.h>
#include <stdint.h>

typedef unsigned short u16;
typedef __attribute__((ext_vector_type(8))) short short8;
typedef __attribute__((ext_vector_type(4))) float f32x4;

#define D_    256
#define NH_   8
#define HD_   32
#define LV_   21760
#define DFF_  1024
#define EPS_  1e-5f
#define MH_   21760   // rows per half (total M = 43520)
#define MT_   43520

__device__ __forceinline__ float bf2f(u16 u) {
    union { uint32_t i; float f; } x; x.i = ((uint32_t)u) << 16; return x.f;
}
// hardware packed f32x2 -> bf16x2 (RNE), 1 instruction
__device__ __forceinline__ uint32_t pk2(float a, float b) {
    uint32_t r;
    asm("v_cvt_pk_bf16_f32 %0, %1, %2" : "=v"(r) : "v"(a), "v"(b));
    return r;
}
__device__ __forceinline__ u16 f2bf(float f) {
    return (u16)(pk2(f, f) & 0xffffu);
}
__device__ __forceinline__ float blo(uint32_t u) {
    union { uint32_t i; float f; } x; x.i = u << 16; return x.f;
}
__device__ __forceinline__ float bhi(uint32_t u) {
    union { uint32_t i; float f; } x; x.i = u & 0xffff0000u; return x.f;
}
__device__ __forceinline__ void cv8(u16* dst, float4 a, float4 b) {
    uint4 r;
    r.x = pk2(a.x, a.y); r.y = pk2(a.z, a.w);
    r.z = pk2(b.x, b.y); r.w = pk2(b.z, b.w);
    *(uint4*)dst = r;
}
__device__ __forceinline__ void cv8add(u16* dst, float4 a, float4 a2, float4 b, float4 b2) {
    uint4 r;
    r.x = pk2(a.x + a2.x, a.y + a2.y); r.y = pk2(a.z + a2.z, a.w + a2.w);
    r.z = pk2(b.x + b2.x, b.y + b2.y); r.w = pk2(b.z + b2.z, b.w + b2.w);
    *(uint4*)dst = r;
}

// ---------------- K0: f32 -> bf16 weight conversion ----------------
__global__ __launch_bounds__(256) void k_cvt(const float* __restrict__ in,
                                             u16* __restrict__ out, int n4) {
    int i = blockIdx.x * 256 + threadIdx.x;
    if (i < n4) {
        float4 v = ((const float4*)in)[i];
        uint2 r; r.x = pk2(v.x, v.y); r.y = pk2(v.z, v.w);
        *(uint2*)(out + (size_t)i * 4) = r;
    }
}

// ---------------- K1: MFMA value projection (BM=128,BN=64) -> bf16 v[b,h,l,hd] ----------------
__global__ __launch_bounds__(256) void k_vprojm(
        const float* __restrict__ src, const float* __restrict__ vpw,
        const float* __restrict__ vpb, u16* __restrict__ vout) {
    __shared__ u16 As[2][128 * 32];
    __shared__ u16 Bs[2][64 * 32];
    const int t = threadIdx.x;
    const int l = t & 63, w = t >> 6;
    const int m0 = blockIdx.x * 128, n0 = blockIdx.y * 64;
    const int r0 = t >> 2, c0 = t & 3;
    const int wsA0 = r0 * 32 + ((c0 ^ ((r0 >> 1) & 3)) << 3);
    const int wsA1 = wsA0 + 64 * 32;             // row+64 keeps same swizzle
    const int wsB  = wsA0;
    const float* gA0 = src + (size_t)(m0 + r0) * 256 + c0 * 8;
    const float* gA1 = gA0 + (size_t)64 * 256;
    const float* gB  = vpw + (size_t)(n0 + r0) * 256 + c0 * 8;
    const int fr = l & 15, fg = l >> 4;
    const int wm = w >> 1, wn = w & 1;

    f32x4 acc[4][2];
    #pragma unroll
    for (int mi = 0; mi < 4; ++mi)
        #pragma unroll
        for (int ni = 0; ni < 2; ++ni)
            acc[mi][ni] = (f32x4){0.f, 0.f, 0.f, 0.f};

    cv8(&As[0][wsA0], *(const float4*)gA0, *(const float4*)(gA0 + 4));
    cv8(&As[0][wsA1], *(const float4*)gA1, *(const float4*)(gA1 + 4));
    cv8(&Bs[0][wsB],  *(const float4*)gB,  *(const float4*)(gB + 4));
    __syncthreads();

    for (int kt = 0; kt < 8; ++kt) {
        const int cur = kt & 1;
        float4 na0, na1, na2, na3, nb0, nb1;
        if (kt < 7) {
            na0 = *(const float4*)(gA0 + (kt + 1) * 32);
            na1 = *(const float4*)(gA0 + (kt + 1) * 32 + 4);
            na2 = *(const float4*)(gA1 + (kt + 1) * 32);
            na3 = *(const float4*)(gA1 + (kt + 1) * 32 + 4);
            nb0 = *(const float4*)(gB + (kt + 1) * 32);
            nb1 = *(const float4*)(gB + (kt + 1) * 32 + 4);
        }
        short8 af[4], bfr[2];
        #pragma unroll
        for (int mi = 0; mi < 4; ++mi) {
            const int r = wm * 64 + mi * 16 + fr;
            af[mi] = *(const short8*)&As[cur][r * 32 + ((fg ^ ((r >> 1) & 3)) << 3)];
        }
        #pragma unroll
        for (int ni = 0; ni < 2; ++ni) {
            const int r = wn * 32 + ni * 16 + fr;
            bfr[ni] = *(const short8*)&Bs[cur][r * 32 + ((fg ^ ((r >> 1) & 3)) << 3)];
        }
        #pragma unroll
        for (int mi = 0; mi < 4; ++mi)
            #pragma unroll
            for (int ni = 0; ni < 2; ++ni)
                acc[mi][ni] = __builtin_amdgcn_mfma_f32_16x16x32_bf16(af[mi], bfr[ni], acc[mi][ni], 0, 0, 0);
        if (kt < 7) {
            cv8(&As[cur ^ 1][wsA0], na0, na1);
            cv8(&As[cur ^ 1][wsA1], na2, na3);
            cv8(&Bs[cur ^ 1][wsB],  nb0, nb1);
            __syncthreads();
        }
    }
    const int b = m0 / LV_;          // 21760 % 128 == 0, no straddle
    #pragma unroll
    for (int ni = 0; ni < 2; ++ni) {
        const int n = n0 + wn * 32 + ni * 16 + fr;
        const float bv = vpb[n];
        const int h = n >> 5, hd = n & 31;
        #pragma unroll
        for (int mi = 0; mi < 4; ++mi) {
            #pragma unroll
            for (int q = 0; q < 4; ++q) {
                const int m = m0 + wm * 64 + mi * 16 + fg * 4 + q;
                const int lrow = m - b * LV_;
                vout[((size_t)(b * NH_ + h) * LV_ + lrow) * HD_ + hd] = f2bf(acc[mi][ni][q] + bv);
            }
        }
    }
}

// ---------------- K2: MFMA logits (BM=128,BN=64) -> bf16 [M][head][att16|box16] ----------------
__global__ __launch_bounds__(256) void k_logits(
        const float* __restrict__ src, const float* __restrict__ pos,
        const float* __restrict__ attw, const float* __restrict__ attb,
        const float* __restrict__ boxw, const float* __restrict__ boxb,
        u16* __restrict__ lgout) {
    __shared__ u16 As[2][128 * 32];
    __shared__ u16 Bs[2][64 * 32];
    const int t = threadIdx.x;
    const int l = t & 63, w = t >> 6;
    const int m0 = blockIdx.x * 128;
    const int n0g = blockIdx.y * 64;
    const float* Bsrc = (n0g < 128) ? (attw + (size_t)n0g * 256) : (boxw + (size_t)(n0g - 128) * 256);
    const float* bsrc = (n0g < 128) ? (attb + n0g) : (boxb + (n0g - 128));
    const int r0 = t >> 2, c0 = t & 3;
    const int wsA0 = r0 * 32 + ((c0 ^ ((r0 >> 1) & 3)) << 3);
    const int wsA1 = wsA0 + 64 * 32;
    const int wsB  = wsA0;
    const float* gAs0 = src + (size_t)(m0 + r0) * 256 + c0 * 8;
    const float* gAp0 = pos + (size_t)(m0 + r0) * 256 + c0 * 8;
    const float* gAs1 = gAs0 + (size_t)64 * 256;
    const float* gAp1 = gAp0 + (size_t)64 * 256;
    const float* gB   = Bsrc + (size_t)r0 * 256 + c0 * 8;
    const int fr = l & 15, fg = l >> 4;
    const int wm = w >> 1, wn = w & 1;

    f32x4 acc[4][2];
    #pragma unroll
    for (int mi = 0; mi < 4; ++mi)
        #pragma unroll
        for (int ni = 0; ni < 2; ++ni)
            acc[mi][ni] = (f32x4){0.f, 0.f, 0.f, 0.f};

    cv8add(&As[0][wsA0], *(const float4*)gAs0, *(const float4*)gAp0,
                         *(const float4*)(gAs0 + 4), *(const float4*)(gAp0 + 4));
    cv8add(&As[0][wsA1], *(const float4*)gAs1, *(const float4*)gAp1,
                         *(const float4*)(gAs1 + 4), *(const float4*)(gAp1 + 4));
    cv8(&Bs[0][wsB], *(const float4*)gB, *(const float4*)(gB + 4));
    __syncthreads();

    for (int kt = 0; kt < 8; ++kt) {
        const int cur = kt & 1;
        float4 ns0, ns1, np0, np1, ns2, ns3, np2, np3, nb0, nb1;
        if (kt < 7) {
            ns0 = *(const float4*)(gAs0 + (kt + 1) * 32);
            ns1 = *(const float4*)(gAs0 + (kt + 1) * 32 + 4);
            np0 = *(const float4*)(gAp0 + (kt + 1) * 32);
            np1 = *(const float4*)(gAp0 + (kt + 1) * 32 + 4);
            ns2 = *(const float4*)(gAs1 + (kt + 1) * 32);
            ns3 = *(const float4*)(gAs1 + (kt + 1) * 32 + 4);
            np2 = *(const float4*)(gAp1 + (kt + 1) * 32);
            np3 = *(const float4*)(gAp1 + (kt + 1) * 32 + 4);
            nb0 = *(const float4*)(gB + (kt + 1) * 32);
            nb1 = *(const float4*)(gB + (kt + 1) * 32 + 4);
        }
        short8 af[4], bfr[2];
        #pragma unroll
        for (int mi = 0; mi < 4; ++mi) {
            const int r = wm * 64 + mi * 16 + fr;
            af[mi] = *(const short8*)&As[cur][r * 32 + ((fg ^ ((r >> 1) & 3)) << 3)];
        }
        #pragma unroll
        for (int ni = 0; ni < 2; ++ni) {
            const int r = wn * 32 + ni * 16 + fr;
            bfr[ni] = *(const short8*)&Bs[cur][r * 32 + ((fg ^ ((r >> 1) & 3)) << 3)];
        }
        #pragma unroll
        for (int mi = 0; mi < 4; ++mi)
            #pragma unroll
            for (int ni = 0; ni < 2; ++ni)
                acc[mi][ni] = __builtin_amdgcn_mfma_f32_16x16x32_bf16(af[mi], bfr[ni], acc[mi][ni], 0, 0, 0);
        if (kt < 7) {
            cv8add(&As[cur ^ 1][wsA0], ns0, np0, ns1, np1);
            cv8add(&As[cur ^ 1][wsA1], ns2, np2, ns3, np3);
            cv8(&Bs[cur ^ 1][wsB], nb0, nb1);
            __syncthreads();
        }
    }
    #pragma unroll
    for (int ni = 0; ni < 2; ++ni) {
        const int nl_ = wn * 32 + ni * 16 + fr;
        const int n = n0g + nl_;
        const float bv = bsrc[nl_];
        const int off = (n < 128) ? ((n >> 4) * 32 + (n & 15))
                                  : (((n - 128) >> 4) * 32 + 16 + ((n - 128) & 15));
        #pragma unroll
        for (int mi = 0; mi < 4; ++mi) {
            #pragma unroll
            for (int q = 0; q < 4; ++q) {
                const int m = m0 + wm * 64 + mi * 16 + fg * 4 + q;
                lgout[(size_t)m * 256 + off] = f2bf(acc[mi][ni][q] + bv);
            }
        }
    }
}

// ---------------- K3: sampling, (batch, head-pair)-split for L2 residency ----------------
// grid = 10880 = 8 combos x 1360 row-groups; combo = bid&7 -> pinned XCD.
// CWI layout [g][corner-pair][34] uint2: conflict-light writes & reads.
__global__ __launch_bounds__(256) void k_sample(
        const u16* __restrict__ lg, const float* __restrict__ refw,
        const u16* __restrict__ vws, u16* __restrict__ smp) {
    __shared__ float LG[16][2][36];                 // padded strides (72/36 words)
    __shared__ float RW[16][8];
    __shared__ __align__(16) uint2 CWI[32 * 68];    // g*68 + P*34 + u*2 + (c&1)
    const int t = threadIdx.x;
    const int bid = blockIdx.x;
    const int combo = bid & 7;            // -> XCD (round-robin dispatch)
    const int idx = bid >> 3;             // 0..1359
    const int b = combo >> 2, hp = combo & 3;
    const int h0 = hp * 2;
    const long gr0 = (long)b * LV_ + (long)idx * 16;
    const uint32_t PLANEB = (uint32_t)LV_ * HD_ * 2;   // bytes per (b,h) plane

    // ---- stage logits slice (bf16 -> f32) + refw ----
    {
        const int row = t >> 4, part = t & 15;      // 16 parts x 4 vals = 64 per row
        const uint2 v = *(const uint2*)(lg + (size_t)(gr0 + row) * 256 + h0 * 32 + part * 4);
        const int hs = part >> 3, kk = (part & 7) * 4;
        LG[row][hs][kk]     = blo(v.x);
        LG[row][hs][kk + 1] = bhi(v.x);
        LG[row][hs][kk + 2] = blo(v.y);
        LG[row][hs][kk + 3] = bhi(v.y);
        if (t < 112) {
            int r2 = t / 7, k = t % 7;
            RW[r2][k] = refw[(gr0 + r2) * 7 + k];
        }
    }
    __syncthreads();
    // ---- softmax over 16 att values per (row, head) ----
    if (t < 32) {
        const int row = t >> 1, hs = t & 1;
        float* a = LG[row][hs];
        float m = a[0];
        #pragma unroll
        for (int k = 1; k < 16; ++k) m = fmaxf(m, a[k]);
        float s = 0.f;
        float e[16];
        #pragma unroll
        for (int k = 0; k < 16; ++k) { e[k] = __expf(a[k] - m); s += e[k]; }
        const float inv = 1.f / s;
        #pragma unroll
        for (int k = 0; k < 16; ++k) a[k] = e[k] * inv;
    }
    __syncthreads();
    // ---- corner compute: 512 units = (16 rows x 2 hs x 4 nl x 4 p), 2 per thread ----
    #pragma unroll
    for (int uu = 0; uu < 2; ++uu) {
        const int u = t + uu * 256;
        const int row = u >> 5, rem = u & 31;
        const int hs = rem >> 4, nl = (rem >> 2) & 3, p = rem & 3;
        const float rw0 = RW[row][0], rw1 = RW[row][1], rw3 = RW[row][3], rw4 = RW[row][4], ang = RW[row][6];
        const float ob0 = LG[row][hs][16 + nl * 4 + 0];
        const float ob1 = LG[row][hs][16 + nl * 4 + 1];
        const float ob2 = LG[row][hs][16 + nl * 4 + 2];
        const float ob3 = LG[row][hs][16 + nl * 4 + 3];
        const float cx = rw0 + ob0 * 0.125f * rw3;
        const float cy = rw1 + ob1 * 0.125f * rw4;
        const float bw = fmaxf(rw3 + ob2 * 0.125f * rw3, 0.f);
        const float bh = fmaxf(rw4 + ob3 * 0.125f * rw4, 0.f);
        const float kx = (p & 1) ? 0.25f : -0.25f;
        const float ky = (p >> 1) ? 0.25f : -0.25f;
        float sth, cth;
        __sincosf(ang, &sth, &cth);
        const float g0 = kx * bw, g1 = ky * bh;
        const float gx = cx + g0 * cth - g1 * sth;
        const float gy = cy + g0 * sth + g1 * cth;
        const int Wl = 128 >> nl;
        const int st = (65536 - (65536 >> (2 * nl))) / 3;
        const float x = gx * Wl - 0.5f, y = gy * Wl - 0.5f;
        const float xf = floorf(x), yf = floorf(y);
        const float wx = x - xf, wy = y - yf;
        const int x0 = (int)xf, y0 = (int)yf;
        const float awv = LG[row][hs][nl * 4 + p];
        const uint32_t hoff = hs ? PLANEB : 0u;
        uint2 cw[4];
        #pragma unroll
        for (int c4 = 0; c4 < 4; ++c4) {
            const int dx = c4 & 1, dy = c4 >> 1;
            const int xi = x0 + dx, yi = y0 + dy;
            const float wgt = (dx ? wx : 1.f - wx) * (dy ? wy : 1.f - wy);
            const bool valid = (xi >= 0) && (xi < Wl) && (yi >= 0) && (yi < Wl);
            const int xc = xi < 0 ? 0 : (xi > Wl - 1 ? Wl - 1 : xi);
            const int yc = yi < 0 ? 0 : (yi > Wl - 1 ? Wl - 1 : yi);
            const float wv = valid ? wgt * awv : 0.f;
            cw[c4].x = __float_as_uint(wv);
            cw[c4].y = (uint32_t)(st + yc * Wl + xc) * 64u + hoff;  // byte offset incl. head plane
        }
        const int g = row * 2 + hs, un = nl * 4 + p;
        uint2* d0 = &CWI[g * 68 + un * 2];
        *(uint4*)(d0)      = *(const uint4*)&cw[0];    // corners 0,1
        *(uint4*)(d0 + 34) = *(const uint4*)&cw[2];    // corners 2,3
    }
    __syncthreads();
    // ---- gather: group g=(row,hs), lane e covers hd e*4..e*4+3 ----
    {
        const int e = t & 7, g = t >> 3;
        const int row = g >> 1, hs = g & 1;
        const char* vbp = (const char*)vws +
            (((size_t)(b * NH_ + h0) * LV_) * HD_ + e * 4) * 2;
        const uint2* cbase = &CWI[g * 68];
        float a0 = 0.f, a1 = 0.f, a2 = 0.f, a3 = 0.f;
        #pragma unroll 4
        for (int k = 0; k < 16; ++k) {
            #pragma unroll
            for (int cc = 0; cc < 2; ++cc) {
                const uint4 cw2 = *(const uint4*)&cbase[cc * 34 + k * 2];
                const float w0 = __uint_as_float(cw2.x);
                const uint2 d0 = *(const uint2*)(vbp + cw2.y);
                const float w1 = __uint_as_float(cw2.z);
                const uint2 d1 = *(const uint2*)(vbp + cw2.w);
                a0 += w0 * blo(d0.x); a1 += w0 * bhi(d0.x);
                a2 += w0 * blo(d0.y); a3 += w0 * bhi(d0.y);
                a0 += w1 * blo(d1.x); a1 += w1 * bhi(d1.x);
                a2 += w1 * blo(d1.y); a3 += w1 * bhi(d1.y);
            }
        }
        uint2 o; o.x = pk2(a0, a1); o.y = pk2(a2, a3);
        *(uint2*)(smp + (size_t)(gr0 + row) * 256 + (h0 + hs) * 32 + e * 4) = o;
    }
}

// ---------------- K4: MFMA out-proj (BM=64,BN=256) + residual + LN1 -> src1b bf16 ----------------
__global__ __launch_bounds__(256) void k_oproj(
        const u16* __restrict__ A,      // SMP [MT_][256] bf16
        const float* __restrict__ opw,  // [256][256] f32
        const float* __restrict__ opb,
        const float* __restrict__ src,  // residual f32
        const float* __restrict__ lnw, const float* __restrict__ lnb,
        u16* __restrict__ out) {        // src1b [MT_][256] bf16
    __shared__ char smem[40960];
    u16* As = (u16*)smem;               // [2][64*32]  (8 KB)
    u16* Bs = (u16*)(smem + 8192);      // [2][256*32] (32 KB)
    u16* Y  = (u16*)smem;               // [64][256] bf16 overlay (32 KB)
    const int t = threadIdx.x;
    const int l = t & 63, w = t >> 6;
    const int m0 = blockIdx.x * 64;
    const int r0 = t >> 2, sc = t & 3;
    const int aslot = r0 * 32 + ((sc ^ ((r0 >> 1) & 3)) << 3);
    const u16* gA = A + (size_t)(m0 + r0) * 256 + sc * 8;
    const float* gB[4];
    int bslot[4];
    #pragma unroll
    for (int i = 0; i < 4; ++i) {
        const int r = r0 + i * 64;
        gB[i] = opw + (size_t)r * 256 + sc * 8;
        bslot[i] = r * 32 + ((sc ^ ((r >> 1) & 3)) << 3);
    }
    const int fr = l & 15, fg = l >> 4;

    f32x4 acc[4][4];
    #pragma unroll
    for (int mi = 0; mi < 4; ++mi)
        #pragma unroll
        for (int ni = 0; ni < 4; ++ni)
            acc[mi][ni] = (f32x4){0.f, 0.f, 0.f, 0.f};

    *(uint4*)&As[aslot] = *(const uint4*)gA;
    #pragma unroll
    for (int i = 0; i < 4; ++i)
        cv8(&Bs[bslot[i]], *(const float4*)gB[i], *(const float4*)(gB[i] + 4));
    __syncthreads();

    for (int kt = 0; kt < 8; ++kt) {
        const int cur = kt & 1;
        uint4 na; float4 nb[4][2];
        if (kt < 7) {
            na = *(const uint4*)(gA + (kt + 1) * 32);
            #pragma unroll
            for (int i = 0; i < 4; ++i) {
                nb[i][0] = *(const float4*)(gB[i] + (kt + 1) * 32);
                nb[i][1] = *(const float4*)(gB[i] + (kt + 1) * 32 + 4);
            }
        }
        short8 af[4], bfr[4];
        #pragma unroll
        for (int mi = 0; mi < 4; ++mi) {
            const int r = mi * 16 + fr;
            af[mi] = *(const short8*)&As[cur * 2048 + r * 32 + ((fg ^ ((r >> 1) & 3)) << 3)];
        }
        #pragma unroll
        for (int ni = 0; ni < 4; ++ni) {
            const int r = w * 64 + ni * 16 + fr;
            bfr[ni] = *(const short8*)&Bs[cur * 8192 + r * 32 + ((fg ^ ((r >> 1) & 3)) << 3)];
        }
        #pragma unroll
        for (int mi = 0; mi < 4; ++mi)
            #pragma unroll
            for (int ni = 0; ni < 4; ++ni)
                acc[mi][ni] = __builtin_amdgcn_mfma_f32_16x16x32_bf16(af[mi], bfr[ni], acc[mi][ni], 0, 0, 0);
        if (kt < 7) {
            *(uint4*)&As[(cur ^ 1) * 2048 + aslot] = na;
            #pragma unroll
            for (int i = 0; i < 4; ++i)
                cv8(&Bs[(cur ^ 1) * 8192 + bslot[i]], nb[i][0], nb[i][1]);
            __syncthreads();
        }
    }
    __syncthreads();   // staging reads done -> safe to overlay Y
    #pragma unroll
    for (int ni = 0; ni < 4; ++ni) {
        const int n = w * 64 + ni * 16 + fr;
        const float bv = opb[n];
        #pragma unroll
        for (int mi = 0; mi < 4; ++mi) {
            #pragma unroll
            for (int q = 0; q < 4; ++q) {
                const int ml = mi * 16 + fg * 4 + q;
                Y[ml * 256 + n] = f2bf(acc[mi][ni][q] + bv + src[(size_t)(m0 + ml) * 256 + n]);
            }
        }
    }
    __syncthreads();
    // LN: wave w handles rows w*16 .. w*16+15
    for (int rr = 0; rr < 16; ++rr) {
        const int m = w * 16 + rr;
        const float v0 = bf2f(Y[m * 256 + l]);
        const float v1 = bf2f(Y[m * 256 + 64 + l]);
        const float v2 = bf2f(Y[m * 256 + 128 + l]);
        const float v3 = bf2f(Y[m * 256 + 192 + l]);
        float s1 = v0 + v1 + v2 + v3;
        float s2 = v0 * v0 + v1 * v1 + v2 * v2 + v3 * v3;
        #pragma unroll
        for (int off = 32; off; off >>= 1) {
            s1 += __shfl_xor(s1, off);
            s2 += __shfl_xor(s2, off);
        }
        const float mean = s1 * (1.f / 256.f);
        const float var = s2 * (1.f / 256.f) - mean * mean;
        const float rs = rsqrtf(var + EPS_);
        const size_t ob = (size_t)(m0 + m) * 256;
        out[ob + l]       = f2bf((v0 - mean) * rs * lnw[l]       + lnb[l]);
        out[ob + 64 + l]  = f2bf((v1 - mean) * rs * lnw[64 + l]  + lnb[64 + l]);
        out[ob + 128 + l] = f2bf((v2 - mean) * rs * lnw[128 + l] + lnb[128 + l]);
        out[ob + 192 + l] = f2bf((v3 - mean) * rs * lnw[192 + l] + lnb[192 + l]);
    }
}

// ---------------- K5: MFMA GEMM1: H = relu(src1 @ l1w^T + b), 128x128 tile ----------------
__global__ __launch_bounds__(256) void k_gemm1(
        const u16* __restrict__ A, const u16* __restrict__ Bw,
        const float* __restrict__ bias, u16* __restrict__ H) {
    __shared__ u16 As[2][128 * 32];
    __shared__ u16 Bs[2][128 * 32];
    const int t = threadIdx.x;
    const int l = t & 63, w = t >> 6;
    const int m0 = blockIdx.x * 128, n0 = blockIdx.y * 128;
    const int sr = t >> 1, sc0 = (t & 1) * 2;
    const int ws0 = sr * 32 + ((sc0 ^ ((sr >> 1) & 3)) << 3);
    const int ws1 = sr * 32 + (((sc0 + 1) ^ ((sr >> 1) & 3)) << 3);
    const u16* gA = A + (size_t)(m0 + sr) * 256 + sc0 * 8;
    const u16* gB = Bw + (size_t)(n0 + sr) * 256 + sc0 * 8;
    const int fr = l & 15, fg = l >> 4;
    const int wm = w >> 1, wn = w & 1;

    f32x4 acc[4][4];
    #pragma unroll
    for (int mi = 0; mi < 4; ++mi)
        #pragma unroll
        for (int ni = 0; ni < 4; ++ni)
            acc[mi][ni] = (f32x4){0.f, 0.f, 0.f, 0.f};

    *(uint4*)&As[0][ws0] = *(const uint4*)(gA);
    *(uint4*)&As[0][ws1] = *(const uint4*)(gA + 8);
    *(uint4*)&Bs[0][ws0] = *(const uint4*)(gB);
    *(uint4*)&Bs[0][ws1] = *(const uint4*)(gB + 8);
    __syncthreads();

    for (int kt = 0; kt < 8; ++kt) {
        const int cur = kt & 1;
        uint4 na0, na1, nb0, nb1;
        if (kt < 7) {
            na0 = *(const uint4*)(gA + (kt + 1) * 32);
            na1 = *(const uint4*)(gA + (kt + 1) * 32 + 8);
            nb0 = *(const uint4*)(gB + (kt + 1) * 32);
            nb1 = *(const uint4*)(gB + (kt + 1) * 32 + 8);
        }
        short8 af[4], bfr[4];
        #pragma unroll
        for (int mi = 0; mi < 4; ++mi) {
            const int r = wm * 64 + mi * 16 + fr;
            af[mi] = *(const short8*)&As[cur][r * 32 + ((fg ^ ((r >> 1) & 3)) << 3)];
        }
        #pragma unroll
        for (int ni = 0; ni < 4; ++ni) {
            const int r = wn * 64 + ni * 16 + fr;
            bfr[ni] = *(const short8*)&Bs[cur][r * 32 + ((fg ^ ((r >> 1) & 3)) << 3)];
        }
        #pragma unroll
        for (int mi = 0; mi < 4; ++mi)
            #pragma unroll
            for (int ni = 0; ni < 4; ++ni)
                acc[mi][ni] = __builtin_amdgcn_mfma_f32_16x16x32_bf16(af[mi], bfr[ni], acc[mi][ni], 0, 0, 0);
        if (kt < 7) {
            *(uint4*)&As[cur ^ 1][ws0] = na0;
            *(uint4*)&As[cur ^ 1][ws1] = na1;
            *(uint4*)&Bs[cur ^ 1][ws0] = nb0;
            *(uint4*)&Bs[cur ^ 1][ws1] = nb1;
            __syncthreads();
        }
    }
    #pragma unroll
    for (int ni = 0; ni < 4; ++ni) {
        const int n = n0 + wn * 64 + ni * 16 + fr;
        const float bv = bias[n];
        #pragma unroll
        for (int mi = 0; mi < 4; ++mi) {
            #pragma unroll
            for (int q = 0; q < 4; ++q) {
                const int m = m0 + wm * 64 + mi * 16 + fg * 4 + q;
                const float v = acc[mi][ni][q] + bv;
                H[(size_t)m * 1024 + n] = f2bf(fmaxf(v, 0.f));
            }
        }
    }
}

// ---------------- K6: MFMA GEMM2 + bias + residual + LN2 -> f32 out ----------------
__global__ __launch_bounds__(256) void k_gemm2(
        const u16* __restrict__ A, const u16* __restrict__ Bw,
        const float* __restrict__ bias, const u16* __restrict__ resid,
        const float* __restrict__ lnw, const float* __restrict__ lnb,
        float* __restrict__ out) {
    __shared__ char smem[36864];
    u16* As = (u16*)smem;
    u16* Bs = (u16*)(smem + 4096);
    float* Y = (float*)smem;
    const int t = threadIdx.x;
    const int l = t & 63, w = t >> 6;
    const int m0 = blockIdx.x * 32;
    const int sAr = t >> 2, sc = t & 3;
    const int aslot = sAr * 32 + ((sc ^ ((sAr >> 1) & 3)) << 3);
    const u16* gA = A + (size_t)(m0 + sAr) * 1024 + sc * 8;
    const u16* gB[4];
    int bslot[4];
    #pragma unroll
    for (int i = 0; i < 4; ++i) {
        const int r = (t >> 2) + i * 64;
        gB[i] = Bw + (size_t)r * 1024 + sc * 8;
        bslot[i] = r * 32 + ((sc ^ ((r >> 1) & 3)) << 3);
    }
    const int fr = l & 15, fg = l >> 4;

    f32x4 acc[2][4];
    #pragma unroll
    for (int mi = 0; mi < 2; ++mi)
        #pragma unroll
        for (int ni = 0; ni < 4; ++ni)
            acc[mi][ni] = (f32x4){0.f, 0.f, 0.f, 0.f};

    if (t < 128) *(uint4*)&As[aslot] = *(const uint4*)(gA);
    #pragma unroll
    for (int i = 0; i < 4; ++i) *(uint4*)&Bs[bslot[i]] = *(const uint4*)(gB[i]);
    __syncthreads();

    for (int kt = 0; kt < 32; ++kt) {
        const int cur = kt & 1;
        uint4 na, nb[4];
        if (kt < 31) {
            if (t < 128) na = *(const uint4*)(gA + (kt + 1) * 32);
            #pragma unroll
            for (int i = 0; i < 4; ++i) nb[i] = *(const uint4*)(gB[i] + (kt + 1) * 32);
        }
        short8 af[2], bfr[4];
        #pragma unroll
        for (int mi = 0; mi < 2; ++mi) {
            const int r = mi * 16 + fr;
            af[mi] = *(const short8*)&As[cur * 1024 + r * 32 + ((fg ^ ((r >> 1) & 3)) << 3)];
        }
        #pragma unroll
        for (int ni = 0; ni < 4; ++ni) {
            const int r = w * 64 + ni * 16 + fr;
            bfr[ni] = *(const short8*)&Bs[cur * 8192 + r * 32 + ((fg ^ ((r >> 1) & 3)) << 3)];
        }
        #pragma unroll
        for (int mi = 0; mi < 2; ++mi)
            #pragma unroll
            for (int ni = 0; ni < 4; ++ni)
                acc[mi][ni] = __builtin_amdgcn_mfma_f32_16x16x32_bf16(af[mi], bfr[ni], acc[mi][ni], 0, 0, 0);
        if (kt < 31) {
            if (t < 128) *(uint4*)&As[(cur ^ 1) * 1024 + aslot] = na;
            #pragma unroll
            for (int i = 0; i < 4; ++i) *(uint4*)&Bs[(cur ^ 1) * 8192 + bslot[i]] = nb[i];
            __syncthreads();
        }
    }
    __syncthreads();
    #pragma unroll
    for (int ni = 0; ni < 4; ++ni) {
        const int n = w * 64 + ni * 16 + fr;
        const float bv = bias[n];
        #pragma unroll
        for (int mi = 0; mi < 2; ++mi) {
            #pragma unroll
            for (int q = 0; q < 4; ++q) {
                const int ml = mi * 16 + fg * 4 + q;
                Y[ml * 256 + n] = acc[mi][ni][q] + bv + bf2f(resid[(size_t)(m0 + ml) * 256 + n]);
            }
        }
    }
    __syncthreads();
    for (int rr = 0; rr < 8; ++rr) {
        const int m = w * 8 + rr;
        const float v0 = Y[m * 256 + l];
        const float v1 = Y[m * 256 + 64 + l];
        const float v2 = Y[m * 256 + 128 + l];
        const float v3 = Y[m * 256 + 192 + l];
        float s1 = v0 + v1 + v2 + v3;
        float s2 = v0 * v0 + v1 * v1 + v2 * v2 + v3 * v3;
        #pragma unroll
        for (int off = 32; off; off >>= 1) {
            s1 += __shfl_xor(s1, off);
            s2 += __shfl_xor(s2, off);
        }
        const float mean = s1 * (1.f / 256.f);
        const float var = s2 * (1.f / 256.f) - mean * mean;
        const float rs = rsqrtf(var + EPS_);
        const size_t ob = (size_t)(m0 + m) * 256;
        out[ob + l]        = (v0 - mean) * rs * lnw[l]        + lnb[l];
        out[ob + 64 + l]   = (v1 - mean) * rs * lnw[64 + l]   + lnb[64 + l];
        out[ob + 128 + l]  = (v2 - mean) * rs * lnw[128 + l]  + lnb[128 + l];
        out[ob + 192 + l]  = (v3 - mean) * rs * lnw[192 + l]  + lnb[192 + l];
    }
}

extern "C" void kernel_launch(void* const* d_in, const int* in_sizes, int n_in,
                              void* d_out, int out_size, void* d_ws, size_t ws_size,
                              hipStream_t stream) {
    const float* src  = (const float*)d_in[0];
    const float* pos  = (const float*)d_in[1];
    const float* refw = (const float*)d_in[4];
    const float* vpw  = (const float*)d_in[5];
    const float* vpb  = (const float*)d_in[6];
    const float* opw  = (const float*)d_in[7];
    const float* opb  = (const float*)d_in[8];
    const float* boxw = (const float*)d_in[9];
    const float* boxb = (const float*)d_in[10];
    const float* attw = (const float*)d_in[11];
    const float* attb = (const float*)d_in[12];
    const float* l1w  = (const float*)d_in[13];
    const float* l1b  = (const float*)d_in[14];
    const float* l2w  = (const float*)d_in[15];
    const float* l2b  = (const float*)d_in[16];
    const float* ln1w = (const float*)d_in[17];
    const float* ln1b = (const float*)d_in[18];
    const float* ln2w = (const float*)d_in[19];
    const float* ln2b = (const float*)d_in[20];

    // ws layout (89,128,960 B total):
    //  [0, 22282240)         vws bf16            -> after k_sample: l1wb/l2wb (1 MB)
    //  [22282240, 44564480)  logits bf16 (22.3MB)-> after k_sample: src1b (bf16)
    //  [44564480, 89128960)  H half (bf16)       ; smp bf16 at [66846720, 89128960)
    u16*   vws    = (u16*)d_ws;
    u16*   l1wb   = (u16*)d_ws;
    u16*   l2wb   = (u16*)((char*)d_ws + 524288);
    u16*   logitsb= (u16*)((char*)d_ws + 22282240u);
    u16*   src1b  = (u16*)((char*)d_ws + 22282240u);
    u16*   Hbf    = (u16*)((char*)d_ws + 44564480u);
    u16*   smp    = (u16*)((char*)d_ws + 66846720u);

    hipLaunchKernelGGL(k_vprojm, dim3(340, 4), dim3(256), 0, stream, src, vpw, vpb, vws);
    hipLaunchKernelGGL(k_logits, dim3(340, 4), dim3(256), 0, stream,
                       src, pos, attw, attb, boxw, boxb, logitsb);
    hipLaunchKernelGGL(k_sample, dim3(10880), dim3(256), 0, stream, logitsb, refw, vws, smp);
    hipLaunchKernelGGL(k_cvt, dim3(256), dim3(256), 0, stream, l1w, l1wb, 65536);
    hipLaunchKernelGGL(k_cvt, dim3(256), dim3(256), 0, stream, l2w, l2wb, 65536);
    hipLaunchKernelGGL(k_oproj, dim3(680), dim3(256), 0, stream,
                       smp, opw, opb, src, ln1w, ln1b, src1b);
    for (int h = 0; h < 2; ++h) {
        const u16* Ah = src1b + (size_t)h * MH_ * 256;
        float* outh   = (float*)d_out + (size_t)h * MH_ * 256;
        hipLaunchKernelGGL(k_gemm1, dim3(170, 8), dim3(256), 0, stream, Ah, l1wb, l1b, Hbf);
        hipLaunchKernelGGL(k_gemm2, dim3(680), dim3(256), 0, stream, Hbf, l2wb, l2b, Ah, ln2w, ln2b, outh);
    }
}

// Round 8
// 319.597 us; speedup vs baseline: 1.0585x; 1.0585x over previous
//
#include <hip/hip_runtime.h>
#include <stdint.h>

typedef unsigned short u16;
typedef __attribute__((ext_vector_type(8))) short short8;
typedef __attribute__((ext_vector_type(4))) float f32x4;

#define D_    256
#define NH_   8
#define HD_   32
#define LV_   21760
#define DFF_  1024
#define EPS_  1e-5f
#define MH_   21760   // rows per half (total M = 43520)
#define MT_   43520

__device__ __forceinline__ float bf2f(u16 u) {
    union { uint32_t i; float f; } x; x.i = ((uint32_t)u) << 16; return x.f;
}
__device__ __forceinline__ u16 f2bf(float f) {
    union { float f; uint32_t i; } x; x.f = f;
    uint32_t r = x.i + 0x7FFFu + ((x.i >> 16) & 1u);
    return (u16)(r >> 16);
}
__device__ __forceinline__ uint32_t pk2(float a, float b) {
    return (uint32_t)f2bf(a) | ((uint32_t)f2bf(b) << 16);
}
__device__ __forceinline__ float blo(uint32_t u) {
    union { uint32_t i; float f; } x; x.i = u << 16; return x.f;
}
__device__ __forceinline__ float bhi(uint32_t u) {
    union { uint32_t i; float f; } x; x.i = u & 0xffff0000u; return x.f;
}
__device__ __forceinline__ void cv8(u16* dst, float4 a, float4 b) {
    uint4 r;
    r.x = pk2(a.x, a.y); r.y = pk2(a.z, a.w);
    r.z = pk2(b.x, b.y); r.w = pk2(b.z, b.w);
    *(uint4*)dst = r;
}

// ---------------- K0: f32 -> bf16 conversion for both FFN weights, one launch ----------------
__global__ __launch_bounds__(256) void k_cvt2(const float* __restrict__ in1, u16* __restrict__ out1,
                                              const float* __restrict__ in2, u16* __restrict__ out2) {
    int i = blockIdx.x * 256 + threadIdx.x;     // 0..131071
    const float* in = (i < 65536) ? in1 : in2;
    u16* out = (i < 65536) ? out1 : out2;
    const int j = i & 65535;
    float4 v = ((const float4*)in)[j];
    uint2 r; r.x = pk2(v.x, v.y); r.y = pk2(v.z, v.w);
    *(uint2*)(out + (size_t)j * 4) = r;
}

// ---------------- K1: merged MFMA projection: vproj (y<4) / logits (y>=4) ----------------
// BM=64 BN=64 BK=32, A = src (+pos for logits) f32 cvt-at-stage, B = f32 weights cvt-at-stage.
__global__ __launch_bounds__(256) void k_proj(
        const float* __restrict__ src, const float* __restrict__ pos,
        const float* __restrict__ vpw, const float* __restrict__ vpb,
        const float* __restrict__ attw, const float* __restrict__ attb,
        const float* __restrict__ boxw, const float* __restrict__ boxb,
        u16* __restrict__ vout, u16* __restrict__ lgout) {
    __shared__ u16 As[2][64 * 32];
    __shared__ u16 Bs[2][64 * 32];
    const int t = threadIdx.x;
    const int l = t & 63, w = t >> 6;
    const int m0 = blockIdx.x * 64;
    const int by = blockIdx.y;
    const bool isv = by < 4;
    const int n0 = (by & 3) * 64;
    const float* Bsrc = isv ? (vpw + (size_t)n0 * 256)
                            : ((n0 < 128) ? (attw + (size_t)n0 * 256)
                                          : (boxw + (size_t)(n0 - 128) * 256));
    const float* bsrc = isv ? (vpb + n0)
                            : ((n0 < 128) ? (attb + n0) : (boxb + (n0 - 128)));
    const int sr = t >> 2, sc = t & 3;
    const int wslot = sr * 32 + ((sc ^ ((sr >> 1) & 3)) << 3);
    const float* gAs = src + (size_t)(m0 + sr) * 256 + sc * 8;
    const float* gAp = pos + (size_t)(m0 + sr) * 256 + sc * 8;
    const float* gB  = Bsrc + (size_t)sr * 256 + sc * 8;
    const int fr = l & 15, fg = l >> 4;
    const int wm = w >> 1, wn = w & 1;

    f32x4 acc[2][2];
    #pragma unroll
    for (int mi = 0; mi < 2; ++mi)
        #pragma unroll
        for (int ni = 0; ni < 2; ++ni)
            acc[mi][ni] = (f32x4){0.f, 0.f, 0.f, 0.f};

    {
        float4 a0 = *(const float4*)gAs, a1 = *(const float4*)(gAs + 4);
        if (!isv) {
            float4 p0 = *(const float4*)gAp, p1 = *(const float4*)(gAp + 4);
            a0.x += p0.x; a0.y += p0.y; a0.z += p0.z; a0.w += p0.w;
            a1.x += p1.x; a1.y += p1.y; a1.z += p1.z; a1.w += p1.w;
        }
        cv8(&As[0][wslot], a0, a1);
        cv8(&Bs[0][wslot], *(const float4*)gB, *(const float4*)(gB + 4));
    }
    __syncthreads();

    for (int kt = 0; kt < 8; ++kt) {
        const int cur = kt & 1;
        float4 na0, na1, nb0, nb1;
        if (kt < 7) {
            na0 = *(const float4*)(gAs + (kt + 1) * 32);
            na1 = *(const float4*)(gAs + (kt + 1) * 32 + 4);
            if (!isv) {
                float4 p0 = *(const float4*)(gAp + (kt + 1) * 32);
                float4 p1 = *(const float4*)(gAp + (kt + 1) * 32 + 4);
                na0.x += p0.x; na0.y += p0.y; na0.z += p0.z; na0.w += p0.w;
                na1.x += p1.x; na1.y += p1.y; na1.z += p1.z; na1.w += p1.w;
            }
            nb0 = *(const float4*)(gB + (kt + 1) * 32);
            nb1 = *(const float4*)(gB + (kt + 1) * 32 + 4);
        }
        short8 af[2], bfr[2];
        #pragma unroll
        for (int mi = 0; mi < 2; ++mi) {
            const int r = wm * 32 + mi * 16 + fr;
            af[mi] = *(const short8*)&As[cur][r * 32 + ((fg ^ ((r >> 1) & 3)) << 3)];
        }
        #pragma unroll
        for (int ni = 0; ni < 2; ++ni) {
            const int r = wn * 32 + ni * 16 + fr;
            bfr[ni] = *(const short8*)&Bs[cur][r * 32 + ((fg ^ ((r >> 1) & 3)) << 3)];
        }
        #pragma unroll
        for (int mi = 0; mi < 2; ++mi)
            #pragma unroll
            for (int ni = 0; ni < 2; ++ni)
                acc[mi][ni] = __builtin_amdgcn_mfma_f32_16x16x32_bf16(af[mi], bfr[ni], acc[mi][ni], 0, 0, 0);
        if (kt < 7) {
            cv8(&As[cur ^ 1][wslot], na0, na1);
            cv8(&Bs[cur ^ 1][wslot], nb0, nb1);
            __syncthreads();
        }
    }
    if (isv) {
        const int b = m0 / LV_;          // 21760 % 64 == 0, no straddle
        #pragma unroll
        for (int ni = 0; ni < 2; ++ni) {
            const int n = n0 + wn * 32 + ni * 16 + fr;
            const float bv = bsrc[wn * 32 + ni * 16 + fr];
            const int h = n >> 5, hd = n & 31;
            #pragma unroll
            for (int mi = 0; mi < 2; ++mi) {
                #pragma unroll
                for (int q = 0; q < 4; ++q) {
                    const int m = m0 + wm * 32 + mi * 16 + fg * 4 + q;
                    const int lrow = m - b * LV_;
                    vout[((size_t)(b * NH_ + h) * LV_ + lrow) * HD_ + hd] = f2bf(acc[mi][ni][q] + bv);
                }
            }
        }
    } else {
        #pragma unroll
        for (int ni = 0; ni < 2; ++ni) {
            const int nl_ = wn * 32 + ni * 16 + fr;
            const int n = n0 + nl_;
            const float bv = bsrc[nl_];
            // layout: [m][h*32 + (att? k : 16+k)]
            const int off = (n < 128) ? ((n >> 4) * 32 + (n & 15))
                                      : (((n - 128) >> 4) * 32 + 16 + ((n - 128) & 15));
            #pragma unroll
            for (int mi = 0; mi < 2; ++mi) {
                #pragma unroll
                for (int q = 0; q < 4; ++q) {
                    const int m = m0 + wm * 32 + mi * 16 + fg * 4 + q;
                    lgout[(size_t)m * 256 + off] = f2bf(acc[mi][ni][q] + bv);
                }
            }
        }
    }
}

// ---------------- K3: sampling, (batch, head-pair)-split for L2 residency ----------------
// grid = 10880 = 8 combos x 1360 row-groups; combo = bid&7 -> pinned XCD.
__global__ __launch_bounds__(256) void k_sample(
        const u16* __restrict__ lg, const float* __restrict__ refw,
        const u16* __restrict__ vws, u16* __restrict__ smp) {
    __shared__ float LG[16][2][36];
    __shared__ float RW[16][8];
    __shared__ __align__(16) uint2 CWI[32 * 68];    // g*68 + cpair*34 + u*2
    const int t = threadIdx.x;
    const int bid = blockIdx.x;
    const int combo = bid & 7;            // -> XCD (round-robin dispatch)
    const int idx = bid >> 3;             // 0..1359
    const int b = combo >> 2, hp = combo & 3;
    const int h0 = hp * 2;
    const long gr0 = (long)b * LV_ + (long)idx * 16;
    const uint32_t PLANEB = (uint32_t)LV_ * HD_ * 2;   // bytes per (b,h) plane

    {
        const int row = t >> 4, part = t & 15;
        const uint2 v = *(const uint2*)(lg + (size_t)(gr0 + row) * 256 + h0 * 32 + part * 4);
        const int hs = part >> 3, kk = (part & 7) * 4;
        LG[row][hs][kk]     = blo(v.x);
        LG[row][hs][kk + 1] = bhi(v.x);
        LG[row][hs][kk + 2] = blo(v.y);
        LG[row][hs][kk + 3] = bhi(v.y);
        if (t < 112) {
            int r2 = t / 7, k = t % 7;
            RW[r2][k] = refw[(gr0 + r2) * 7 + k];
        }
    }
    __syncthreads();
    if (t < 32) {
        const int row = t >> 1, hs = t & 1;
        float* a = LG[row][hs];
        float m = a[0];
        #pragma unroll
        for (int k = 1; k < 16; ++k) m = fmaxf(m, a[k]);
        float s = 0.f;
        float e[16];
        #pragma unroll
        for (int k = 0; k < 16; ++k) { e[k] = __expf(a[k] - m); s += e[k]; }
        const float inv = 1.f / s;
        #pragma unroll
        for (int k = 0; k < 16; ++k) a[k] = e[k] * inv;
    }
    __syncthreads();
    #pragma unroll
    for (int uu = 0; uu < 2; ++uu) {
        const int u = t + uu * 256;
        const int row = u >> 5, rem = u & 31;
        const int hs = rem >> 4, nl = (rem >> 2) & 3, p = rem & 3;
        const float rw0 = RW[row][0], rw1 = RW[row][1], rw3 = RW[row][3], rw4 = RW[row][4], ang = RW[row][6];
        const float ob0 = LG[row][hs][16 + nl * 4 + 0];
        const float ob1 = LG[row][hs][16 + nl * 4 + 1];
        const float ob2 = LG[row][hs][16 + nl * 4 + 2];
        const float ob3 = LG[row][hs][16 + nl * 4 + 3];
        const float cx = rw0 + ob0 * 0.125f * rw3;
        const float cy = rw1 + ob1 * 0.125f * rw4;
        const float bw = fmaxf(rw3 + ob2 * 0.125f * rw3, 0.f);
        const float bh = fmaxf(rw4 + ob3 * 0.125f * rw4, 0.f);
        const float kx = (p & 1) ? 0.25f : -0.25f;
        const float ky = (p >> 1) ? 0.25f : -0.25f;
        float sth, cth;
        __sincosf(ang, &sth, &cth);
        const float g0 = kx * bw, g1 = ky * bh;
        const float gx = cx + g0 * cth - g1 * sth;
        const float gy = cy + g0 * sth + g1 * cth;
        const int Wl = 128 >> nl;
        const int st = (65536 - (65536 >> (2 * nl))) / 3;
        const float x = gx * Wl - 0.5f, y = gy * Wl - 0.5f;
        const float xf = floorf(x), yf = floorf(y);
        const float wx = x - xf, wy = y - yf;
        const int x0 = (int)xf, y0 = (int)yf;
        const float awv = LG[row][hs][nl * 4 + p];
        const uint32_t hoff = hs ? PLANEB : 0u;
        uint2 cw[4];
        #pragma unroll
        for (int c4 = 0; c4 < 4; ++c4) {
            const int dx = c4 & 1, dy = c4 >> 1;
            const int xi = x0 + dx, yi = y0 + dy;
            const float wgt = (dx ? wx : 1.f - wx) * (dy ? wy : 1.f - wy);
            const bool valid = (xi >= 0) && (xi < Wl) && (yi >= 0) && (yi < Wl);
            const int xc = xi < 0 ? 0 : (xi > Wl - 1 ? Wl - 1 : xi);
            const int yc = yi < 0 ? 0 : (yi > Wl - 1 ? Wl - 1 : yi);
            const float wv = valid ? wgt * awv : 0.f;
            cw[c4].x = __float_as_uint(wv);
            cw[c4].y = (uint32_t)(st + yc * Wl + xc) * 64u + hoff;
        }
        const int g = row * 2 + hs, un = nl * 4 + p;
        uint2* d0 = &CWI[g * 68 + un * 2];
        *(uint4*)(d0)      = *(const uint4*)&cw[0];
        *(uint4*)(d0 + 34) = *(const uint4*)&cw[2];
    }
    __syncthreads();
    {
        const int e = t & 7, g = t >> 3;
        const int row = g >> 1, hs = g & 1;
        const char* vbp = (const char*)vws +
            (((size_t)(b * NH_ + h0) * LV_) * HD_ + e * 4) * 2;
        const uint2* cbase = &CWI[g * 68];
        float a0 = 0.f, a1 = 0.f, a2 = 0.f, a3 = 0.f;
        #pragma unroll 4
        for (int k = 0; k < 16; ++k) {
            #pragma unroll
            for (int cc = 0; cc < 2; ++cc) {
                const uint4 cw2 = *(const uint4*)&cbase[cc * 34 + k * 2];
                const float w0 = __uint_as_float(cw2.x);
                const uint2 d0 = *(const uint2*)(vbp + cw2.y);
                const float w1 = __uint_as_float(cw2.z);
                const uint2 d1 = *(const uint2*)(vbp + cw2.w);
                a0 += w0 * blo(d0.x); a1 += w0 * bhi(d0.x);
                a2 += w0 * blo(d0.y); a3 += w0 * bhi(d0.y);
                a0 += w1 * blo(d1.x); a1 += w1 * bhi(d1.x);
                a2 += w1 * blo(d1.y); a3 += w1 * bhi(d1.y);
            }
        }
        uint2 o; o.x = pk2(a0, a1); o.y = pk2(a2, a3);
        *(uint2*)(smp + (size_t)(gr0 + row) * 256 + (h0 + hs) * 32 + e * 4) = o;
    }
}

// ---------------- K4: MFMA out-proj (BM=32,BN=256) + residual + LN1 -> src1b bf16 ----------------
__global__ __launch_bounds__(256) void k_oproj(
        const u16* __restrict__ A,
        const float* __restrict__ opw,
        const float* __restrict__ opb,
        const float* __restrict__ src,
        const float* __restrict__ lnw, const float* __restrict__ lnb,
        u16* __restrict__ out) {
    __shared__ char smem[36864];
    u16* As = (u16*)smem;
    u16* Bs = (u16*)(smem + 4096);
    float* Y = (float*)smem;
    const int t = threadIdx.x;
    const int l = t & 63, w = t >> 6;
    const int m0 = blockIdx.x * 32;
    const int sAr = t >> 2, sc = t & 3;
    const int aslot = sAr * 32 + ((sc ^ ((sAr >> 1) & 3)) << 3);
    const u16* gA = A + (size_t)(m0 + sAr) * 256 + sc * 8;
    const float* gB[4];
    int bslot[4];
    #pragma unroll
    for (int i = 0; i < 4; ++i) {
        const int r = (t >> 2) + i * 64;
        gB[i] = opw + (size_t)r * 256 + sc * 8;
        bslot[i] = r * 32 + ((sc ^ ((r >> 1) & 3)) << 3);
    }
    const int fr = l & 15, fg = l >> 4;

    f32x4 acc[2][4];
    #pragma unroll
    for (int mi = 0; mi < 2; ++mi)
        #pragma unroll
        for (int ni = 0; ni < 4; ++ni)
            acc[mi][ni] = (f32x4){0.f, 0.f, 0.f, 0.f};

    if (t < 128) *(uint4*)&As[aslot] = *(const uint4*)gA;
    #pragma unroll
    for (int i = 0; i < 4; ++i)
        cv8(&Bs[bslot[i]], *(const float4*)gB[i], *(const float4*)(gB[i] + 4));
    __syncthreads();

    for (int kt = 0; kt < 8; ++kt) {
        const int cur = kt & 1;
        uint4 na; float4 nb[4][2];
        if (kt < 7) {
            if (t < 128) na = *(const uint4*)(gA + (kt + 1) * 32);
            #pragma unroll
            for (int i = 0; i < 4; ++i) {
                nb[i][0] = *(const float4*)(gB[i] + (kt + 1) * 32);
                nb[i][1] = *(const float4*)(gB[i] + (kt + 1) * 32 + 4);
            }
        }
        short8 af[2], bfr[4];
        #pragma unroll
        for (int mi = 0; mi < 2; ++mi) {
            const int r = mi * 16 + fr;
            af[mi] = *(const short8*)&As[cur * 1024 + r * 32 + ((fg ^ ((r >> 1) & 3)) << 3)];
        }
        #pragma unroll
        for (int ni = 0; ni < 4; ++ni) {
            const int r = w * 64 + ni * 16 + fr;
            bfr[ni] = *(const short8*)&Bs[cur * 8192 + r * 32 + ((fg ^ ((r >> 1) & 3)) << 3)];
        }
        #pragma unroll
        for (int mi = 0; mi < 2; ++mi)
            #pragma unroll
            for (int ni = 0; ni < 4; ++ni)
                acc[mi][ni] = __builtin_amdgcn_mfma_f32_16x16x32_bf16(af[mi], bfr[ni], acc[mi][ni], 0, 0, 0);
        if (kt < 7) {
            if (t < 128) *(uint4*)&As[(cur ^ 1) * 1024 + aslot] = na;
            #pragma unroll
            for (int i = 0; i < 4; ++i)
                cv8(&Bs[(cur ^ 1) * 8192 + bslot[i]], nb[i][0], nb[i][1]);
            __syncthreads();
        }
    }
    __syncthreads();
    #pragma unroll
    for (int ni = 0; ni < 4; ++ni) {
        const int n = w * 64 + ni * 16 + fr;
        const float bv = opb[n];
        #pragma unroll
        for (int mi = 0; mi < 2; ++mi) {
            #pragma unroll
            for (int q = 0; q < 4; ++q) {
                const int ml = mi * 16 + fg * 4 + q;
                Y[ml * 256 + n] = acc[mi][ni][q] + bv + src[(size_t)(m0 + ml) * 256 + n];
            }
        }
    }
    __syncthreads();
    for (int rr = 0; rr < 8; ++rr) {
        const int m = w * 8 + rr;
        const float v0 = Y[m * 256 + l];
        const float v1 = Y[m * 256 + 64 + l];
        const float v2 = Y[m * 256 + 128 + l];
        const float v3 = Y[m * 256 + 192 + l];
        float s1 = v0 + v1 + v2 + v3;
        float s2 = v0 * v0 + v1 * v1 + v2 * v2 + v3 * v3;
        #pragma unroll
        for (int off = 32; off; off >>= 1) {
            s1 += __shfl_xor(s1, off);
            s2 += __shfl_xor(s2, off);
        }
        const float mean = s1 * (1.f / 256.f);
        const float var = s2 * (1.f / 256.f) - mean * mean;
        const float rs = rsqrtf(var + EPS_);
        const size_t ob = (size_t)(m0 + m) * 256;
        out[ob + l]       = f2bf((v0 - mean) * rs * lnw[l]       + lnb[l]);
        out[ob + 64 + l]  = f2bf((v1 - mean) * rs * lnw[64 + l]  + lnb[64 + l]);
        out[ob + 128 + l] = f2bf((v2 - mean) * rs * lnw[128 + l] + lnb[128 + l]);
        out[ob + 192 + l] = f2bf((v3 - mean) * rs * lnw[192 + l] + lnb[192 + l]);
    }
}

// ---------------- K5: MFMA GEMM1: H = relu(src1 @ l1w^T + b), 128x128 tile ----------------
__global__ __launch_bounds__(256) void k_gemm1(
        const u16* __restrict__ A, const u16* __restrict__ Bw,
        const float* __restrict__ bias, u16* __restrict__ H) {
    __shared__ u16 As[2][128 * 32];
    __shared__ u16 Bs[2][128 * 32];
    const int t = threadIdx.x;
    const int l = t & 63, w = t >> 6;
    const int m0 = blockIdx.x * 128, n0 = blockIdx.y * 128;
    const int sr = t >> 1, sc0 = (t & 1) * 2;
    const int ws0 = sr * 32 + ((sc0 ^ ((sr >> 1) & 3)) << 3);
    const int ws1 = sr * 32 + (((sc0 + 1) ^ ((sr >> 1) & 3)) << 3);
    const u16* gA = A + (size_t)(m0 + sr) * 256 + sc0 * 8;
    const u16* gB = Bw + (size_t)(n0 + sr) * 256 + sc0 * 8;
    const int fr = l & 15, fg = l >> 4;
    const int wm = w >> 1, wn = w & 1;

    f32x4 acc[4][4];
    #pragma unroll
    for (int mi = 0; mi < 4; ++mi)
        #pragma unroll
        for (int ni = 0; ni < 4; ++ni)
            acc[mi][ni] = (f32x4){0.f, 0.f, 0.f, 0.f};

    *(uint4*)&As[0][ws0] = *(const uint4*)(gA);
    *(uint4*)&As[0][ws1] = *(const uint4*)(gA + 8);
    *(uint4*)&Bs[0][ws0] = *(const uint4*)(gB);
    *(uint4*)&Bs[0][ws1] = *(const uint4*)(gB + 8);
    __syncthreads();

    for (int kt = 0; kt < 8; ++kt) {
        const int cur = kt & 1;
        uint4 na0, na1, nb0, nb1;
        if (kt < 7) {
            na0 = *(const uint4*)(gA + (kt + 1) * 32);
            na1 = *(const uint4*)(gA + (kt + 1) * 32 + 8);
            nb0 = *(const uint4*)(gB + (kt + 1) * 32);
            nb1 = *(const uint4*)(gB + (kt + 1) * 32 + 8);
        }
        short8 af[4], bfr[4];
        #pragma unroll
        for (int mi = 0; mi < 4; ++mi) {
            const int r = wm * 64 + mi * 16 + fr;
            af[mi] = *(const short8*)&As[cur][r * 32 + ((fg ^ ((r >> 1) & 3)) << 3)];
        }
        #pragma unroll
        for (int ni = 0; ni < 4; ++ni) {
            const int r = wn * 64 + ni * 16 + fr;
            bfr[ni] = *(const short8*)&Bs[cur][r * 32 + ((fg ^ ((r >> 1) & 3)) << 3)];
        }
        #pragma unroll
        for (int mi = 0; mi < 4; ++mi)
            #pragma unroll
            for (int ni = 0; ni < 4; ++ni)
                acc[mi][ni] = __builtin_amdgcn_mfma_f32_16x16x32_bf16(af[mi], bfr[ni], acc[mi][ni], 0, 0, 0);
        if (kt < 7) {
            *(uint4*)&As[cur ^ 1][ws0] = na0;
            *(uint4*)&As[cur ^ 1][ws1] = na1;
            *(uint4*)&Bs[cur ^ 1][ws0] = nb0;
            *(uint4*)&Bs[cur ^ 1][ws1] = nb1;
            __syncthreads();
        }
    }
    #pragma unroll
    for (int ni = 0; ni < 4; ++ni) {
        const int n = n0 + wn * 64 + ni * 16 + fr;
        const float bv = bias[n];
        #pragma unroll
        for (int mi = 0; mi < 4; ++mi) {
            #pragma unroll
            for (int q = 0; q < 4; ++q) {
                const int m = m0 + wm * 64 + mi * 16 + fg * 4 + q;
                const float v = acc[mi][ni][q] + bv;
                H[(size_t)m * 1024 + n] = f2bf(fmaxf(v, 0.f));
            }
        }
    }
}

// ---------------- K6: MFMA GEMM2 + bias + residual + LN2 -> f32 out ----------------
__global__ __launch_bounds__(256) void k_gemm2(
        const u16* __restrict__ A, const u16* __restrict__ Bw,
        const float* __restrict__ bias, const u16* __restrict__ resid,
        const float* __restrict__ lnw, const float* __restrict__ lnb,
        float* __restrict__ out) {
    __shared__ char smem[36864];
    u16* As = (u16*)smem;
    u16* Bs = (u16*)(smem + 4096);
    float* Y = (float*)smem;
    const int t = threadIdx.x;
    const int l = t & 63, w = t >> 6;
    const int m0 = blockIdx.x * 32;
    const int sAr = t >> 2, sc = t & 3;
    const int aslot = sAr * 32 + ((sc ^ ((sAr >> 1) & 3)) << 3);
    const u16* gA = A + (size_t)(m0 + sAr) * 1024 + sc * 8;
    const u16* gB[4];
    int bslot[4];
    #pragma unroll
    for (int i = 0; i < 4; ++i) {
        const int r = (t >> 2) + i * 64;
        gB[i] = Bw + (size_t)r * 1024 + sc * 8;
        bslot[i] = r * 32 + ((sc ^ ((r >> 1) & 3)) << 3);
    }
    const int fr = l & 15, fg = l >> 4;

    f32x4 acc[2][4];
    #pragma unroll
    for (int mi = 0; mi < 2; ++mi)
        #pragma unroll
        for (int ni = 0; ni < 4; ++ni)
            acc[mi][ni] = (f32x4){0.f, 0.f, 0.f, 0.f};

    if (t < 128) *(uint4*)&As[aslot] = *(const uint4*)(gA);
    #pragma unroll
    for (int i = 0; i < 4; ++i) *(uint4*)&Bs[bslot[i]] = *(const uint4*)(gB[i]);
    __syncthreads();

    for (int kt = 0; kt < 32; ++kt) {
        const int cur = kt & 1;
        uint4 na, nb[4];
        if (kt < 31) {
            if (t < 128) na = *(const uint4*)(gA + (kt + 1) * 32);
            #pragma unroll
            for (int i = 0; i < 4; ++i) nb[i] = *(const uint4*)(gB[i] + (kt + 1) * 32);
        }
        short8 af[2], bfr[4];
        #pragma unroll
        for (int mi = 0; mi < 2; ++mi) {
            const int r = mi * 16 + fr;
            af[mi] = *(const short8*)&As[cur * 1024 + r * 32 + ((fg ^ ((r >> 1) & 3)) << 3)];
        }
        #pragma unroll
        for (int ni = 0; ni < 4; ++ni) {
            const int r = w * 64 + ni * 16 + fr;
            bfr[ni] = *(const short8*)&Bs[cur * 8192 + r * 32 + ((fg ^ ((r >> 1) & 3)) << 3)];
        }
        #pragma unroll
        for (int mi = 0; mi < 2; ++mi)
            #pragma unroll
            for (int ni = 0; ni < 4; ++ni)
                acc[mi][ni] = __builtin_amdgcn_mfma_f32_16x16x32_bf16(af[mi], bfr[ni], acc[mi][ni], 0, 0, 0);
        if (kt < 31) {
            if (t < 128) *(uint4*)&As[(cur ^ 1) * 1024 + aslot] = na;
            #pragma unroll
            for (int i = 0; i < 4; ++i) *(uint4*)&Bs[(cur ^ 1) * 8192 + bslot[i]] = nb[i];
            __syncthreads();
        }
    }
    __syncthreads();
    #pragma unroll
    for (int ni = 0; ni < 4; ++ni) {
        const int n = w * 64 + ni * 16 + fr;
        const float bv = bias[n];
        #pragma unroll
        for (int mi = 0; mi < 2; ++mi) {
            #pragma unroll
            for (int q = 0; q < 4; ++q) {
                const int ml = mi * 16 + fg * 4 + q;
                Y[ml * 256 + n] = acc[mi][ni][q] + bv + bf2f(resid[(size_t)(m0 + ml) * 256 + n]);
            }
        }
    }
    __syncthreads();
    for (int rr = 0; rr < 8; ++rr) {
        const int m = w * 8 + rr;
        const float v0 = Y[m * 256 + l];
        const float v1 = Y[m * 256 + 64 + l];
        const float v2 = Y[m * 256 + 128 + l];
        const float v3 = Y[m * 256 + 192 + l];
        float s1 = v0 + v1 + v2 + v3;
        float s2 = v0 * v0 + v1 * v1 + v2 * v2 + v3 * v3;
        #pragma unroll
        for (int off = 32; off; off >>= 1) {
            s1 += __shfl_xor(s1, off);
            s2 += __shfl_xor(s2, off);
        }
        const float mean = s1 * (1.f / 256.f);
        const float var = s2 * (1.f / 256.f) - mean * mean;
        const float rs = rsqrtf(var + EPS_);
        const size_t ob = (size_t)(m0 + m) * 256;
        out[ob + l]        = (v0 - mean) * rs * lnw[l]        + lnb[l];
        out[ob + 64 + l]   = (v1 - mean) * rs * lnw[64 + l]   + lnb[64 + l];
        out[ob + 128 + l]  = (v2 - mean) * rs * lnw[128 + l]  + lnb[128 + l];
        out[ob + 192 + l]  = (v3 - mean) * rs * lnw[192 + l]  + lnb[192 + l];
    }
}

extern "C" void kernel_launch(void* const* d_in, const int* in_sizes, int n_in,
                              void* d_out, int out_size, void* d_ws, size_t ws_size,
                              hipStream_t stream) {
    const float* src  = (const float*)d_in[0];
    const float* pos  = (const float*)d_in[1];
    const float* refw = (const float*)d_in[4];
    const float* vpw  = (const float*)d_in[5];
    const float* vpb  = (const float*)d_in[6];
    const float* opw  = (const float*)d_in[7];
    const float* opb  = (const float*)d_in[8];
    const float* boxw = (const float*)d_in[9];
    const float* boxb = (const float*)d_in[10];
    const float* attw = (const float*)d_in[11];
    const float* attb = (const float*)d_in[12];
    const float* l1w  = (const float*)d_in[13];
    const float* l1b  = (const float*)d_in[14];
    const float* l2w  = (const float*)d_in[15];
    const float* l2b  = (const float*)d_in[16];
    const float* ln1w = (const float*)d_in[17];
    const float* ln1b = (const float*)d_in[18];
    const float* ln2w = (const float*)d_in[19];
    const float* ln2b = (const float*)d_in[20];

    // ws layout (89,128,960 B total):
    //  [0, 22282240)         vws bf16            -> after k_sample: l1wb/l2wb (1 MB)
    //  [22282240, 44564480)  logits bf16 (22.3MB)-> after k_sample: src1b (bf16)
    //  [44564480, 89128960)  H half (bf16)       ; smp bf16 at [66846720, 89128960)
    u16*   vws    = (u16*)d_ws;
    u16*   l1wb   = (u16*)d_ws;
    u16*   l2wb   = (u16*)((char*)d_ws + 524288);
    u16*   logitsb= (u16*)((char*)d_ws + 22282240u);
    u16*   src1b  = (u16*)((char*)d_ws + 22282240u);
    u16*   Hbf    = (u16*)((char*)d_ws + 44564480u);
    u16*   smp    = (u16*)((char*)d_ws + 66846720u);

    hipLaunchKernelGGL(k_proj, dim3(680, 8), dim3(256), 0, stream,
                       src, pos, vpw, vpb, attw, attb, boxw, boxb, vws, logitsb);
    hipLaunchKernelGGL(k_sample, dim3(10880), dim3(256), 0, stream, logitsb, refw, vws, smp);
    hipLaunchKernelGGL(k_cvt2, dim3(512), dim3(256), 0, stream, l1w, l1wb, l2w, l2wb);
    hipLaunchKernelGGL(k_oproj, dim3(1360), dim3(256), 0, stream,
                       smp, opw, opb, src, ln1w, ln1b, src1b);
    for (int h = 0; h < 2; ++h) {
        const u16* Ah = src1b + (size_t)h * MH_ * 256;
        float* outh   = (float*)d_out + (size_t)h * MH_ * 256;
        hipLaunchKernelGGL(k_gemm1, dim3(170, 8), dim3(256), 0, stream, Ah, l1wb, l1b, Hbf);
        hipLaunchKernelGGL(k_gemm2, dim3(680), dim3(256), 0, stream, Hbf, l2wb, l2b, Ah, ln2w, ln2b, outh);
    }
}